// Round 1
// baseline (22.960 us; speedup 1.0000x reference)
//
#include <hip/hip_runtime.h>
#include <math.h>

#define N_OSC 2048
#define N_SAMP 16384

// ---------------------------------------------------------------------------
// Kernel 1: per-oscillator prep.
//   amp  = sqrt(p0^2 + p1^2)               (f64, matches np-f64 ref closely)
//   rev  = atan2(p0, amp) / (2*pi)         (revolutions advanced per sample)
// Reference phase at sample s is (s+1)*atan2(p0,amp) radians
//   == 2*pi * (s+1) * rev.
// ---------------------------------------------------------------------------
__global__ __launch_bounds__(256) void prep_kernel(const float* __restrict__ params,
                                                   double* __restrict__ freq_rev,
                                                   float* __restrict__ amp) {
    int o = blockIdx.x * 256 + threadIdx.x;
    if (o < N_OSC) {
        double p0 = (double)params[2 * o + 0];
        double p1 = (double)params[2 * o + 1];
        double a  = sqrt(p0 * p0 + p1 * p1);
        double ang = atan2(p0, a);
        freq_rev[o] = ang * 0.15915494309189535;  // 1/(2*pi)
        amp[o] = (float)a;
    }
}

// ---------------------------------------------------------------------------
// Kernel 2: synthesis. thread = sample, blockIdx.y = oscillator chunk.
// Inner loop indices are block-uniform -> freq/amp reads become scalar loads.
// v_sin_f32 (via __builtin_amdgcn_sinf) takes input in REVOLUTIONS; we
// range-reduce in f64 (u - floor(u)) so the argument is in [0,1).
// ---------------------------------------------------------------------------
template <int OPC>
__global__ __launch_bounds__(256) void synth_kernel(const double* __restrict__ freq_rev,
                                                    const float* __restrict__ amp,
                                                    float* __restrict__ partial) {
    const int s  = blockIdx.x * 256 + threadIdx.x;   // sample index
    const int o0 = blockIdx.y * OPC;                 // oscillator chunk base
    if (s >= N_SAMP) return;
    const double sp1 = (double)(s + 1);

    float acc0 = 0.f, acc1 = 0.f, acc2 = 0.f, acc3 = 0.f;
#pragma unroll 2
    for (int i = 0; i < OPC; i += 4) {
        double u0 = sp1 * freq_rev[o0 + i + 0];
        double u1 = sp1 * freq_rev[o0 + i + 1];
        double u2 = sp1 * freq_rev[o0 + i + 2];
        double u3 = sp1 * freq_rev[o0 + i + 3];
        float r0 = (float)(u0 - floor(u0));
        float r1 = (float)(u1 - floor(u1));
        float r2 = (float)(u2 - floor(u2));
        float r3 = (float)(u3 - floor(u3));
        acc0 = fmaf(amp[o0 + i + 0], __builtin_amdgcn_sinf(r0), acc0);
        acc1 = fmaf(amp[o0 + i + 1], __builtin_amdgcn_sinf(r1), acc1);
        acc2 = fmaf(amp[o0 + i + 2], __builtin_amdgcn_sinf(r2), acc2);
        acc3 = fmaf(amp[o0 + i + 3], __builtin_amdgcn_sinf(r3), acc3);
    }
    partial[blockIdx.y * N_SAMP + s] = (acc0 + acc1) + (acc2 + acc3);
}

// ---------------------------------------------------------------------------
// Kernel 3: reduce oscillator-chunk partials into the output (f64 accumulate).
// ---------------------------------------------------------------------------
__global__ __launch_bounds__(256) void reduce_kernel(const float* __restrict__ partial,
                                                     float* __restrict__ out,
                                                     int chunks) {
    int s = blockIdx.x * 256 + threadIdx.x;
    if (s >= N_SAMP) return;
    double acc = 0.0;
    for (int c = 0; c < chunks; ++c) acc += (double)partial[c * N_SAMP + s];
    out[s] = (float)acc;
}

// ---------------------------------------------------------------------------
// Ultra-fallback (used only if d_ws is tiny): recompute freq/amp inline.
// ---------------------------------------------------------------------------
__global__ __launch_bounds__(256) void inline_kernel(const float* __restrict__ params,
                                                     float* __restrict__ out) {
    int s = blockIdx.x * 256 + threadIdx.x;
    if (s >= N_SAMP) return;
    const double sp1 = (double)(s + 1);
    double acc = 0.0;
    for (int o = 0; o < N_OSC; ++o) {
        double p0 = (double)params[2 * o + 0];
        double p1 = (double)params[2 * o + 1];
        double a  = sqrt(p0 * p0 + p1 * p1);
        double u  = sp1 * (atan2(p0, a) * 0.15915494309189535);
        float  r  = (float)(u - floor(u));
        acc += a * (double)__builtin_amdgcn_sinf(r);
    }
    out[s] = (float)acc;
}

extern "C" void kernel_launch(void* const* d_in, const int* in_sizes, int n_in,
                              void* d_out, int out_size, void* d_ws, size_t ws_size,
                              hipStream_t stream) {
    // d_in[0] = x (unused by the math), d_in[1] = params (2048 x 2 f32)
    const float* params = (const float*)d_in[1];
    float* out = (float*)d_out;

    const size_t freq_bytes = (size_t)N_OSC * sizeof(double);   // 16 KB
    const size_t amp_bytes  = (size_t)N_OSC * sizeof(float);    // 8 KB
    const size_t prep_bytes = freq_bytes + amp_bytes;           // 24 KB
    const int    CHUNKS     = 16;                               // 128 osc each
    const size_t part_bytes = (size_t)CHUNKS * N_SAMP * sizeof(float);  // 1 MB

    if (ws_size >= prep_bytes + part_bytes) {
        double* freq_rev = (double*)d_ws;
        float*  amp      = (float*)((char*)d_ws + freq_bytes);
        float*  partial  = (float*)((char*)d_ws + prep_bytes);
        prep_kernel<<<(N_OSC + 255) / 256, 256, 0, stream>>>(params, freq_rev, amp);
        synth_kernel<N_OSC / 16><<<dim3(N_SAMP / 256, CHUNKS), 256, 0, stream>>>(freq_rev, amp, partial);
        reduce_kernel<<<N_SAMP / 256, 256, 0, stream>>>(partial, out, CHUNKS);
    } else if (ws_size >= prep_bytes) {
        // Single-chunk path: synth writes the final sums straight to d_out.
        double* freq_rev = (double*)d_ws;
        float*  amp      = (float*)((char*)d_ws + freq_bytes);
        prep_kernel<<<(N_OSC + 255) / 256, 256, 0, stream>>>(params, freq_rev, amp);
        synth_kernel<N_OSC><<<dim3(N_SAMP / 256, 1), 256, 0, stream>>>(freq_rev, amp, out);
    } else {
        inline_kernel<<<N_SAMP / 256, 256, 0, stream>>>(params, out);
    }
}

// Round 2
// 14.150 us; speedup vs baseline: 1.6226x; 1.6226x over previous
//
#include <hip/hip_runtime.h>
#include <math.h>

#define N_OSC 2048
#define N_SAMP 16384
#define CHUNKS 16
#define OPC (N_OSC / CHUNKS)   // 128 oscillators per chunk

// ---------------------------------------------------------------------------
// Fused kernel: per-block oscillator prep (LDS) + synthesis.
//
// Math: ref phase at sample s is (s+1)*atan2(p0, amp) radians
//       = 2*pi * (s+1) * rev,  rev = atan2(p0, amp)/(2*pi)  in (0, 0.125].
// v_sin_f32 takes REVOLUTIONS, so we need frac((s+1)*rev) accurately.
// Split rev = hi + lo with hi's mantissa truncated to 10 significant bits:
// (s+1) <= 2^14 is an exact integer, so (s+1)*hi is EXACT in f32
// (14+10 = 24-bit product). Then
//   frac((s+1)*rev) = frac( frac((s+1)*hi) + (s+1)*lo )   (error ~2e-7 rev).
// ---------------------------------------------------------------------------
__global__ __launch_bounds__(256) void synth_fused(const float* __restrict__ params,
                                                   float* __restrict__ partial) {
    __shared__ float sh_hi[OPC];
    __shared__ float sh_lo[OPC];
    __shared__ float sh_amp[OPC];

    const int tx = threadIdx.x;
    const int o0 = blockIdx.y * OPC;

    if (tx < OPC) {
        double p0  = (double)params[2 * (o0 + tx) + 0];
        double p1  = (double)params[2 * (o0 + tx) + 1];
        double a   = sqrt(p0 * p0 + p1 * p1);
        double rev = atan2(p0, a) * 0.15915494309189535;   // /(2*pi), in (0,0.125]
        float hi = (float)rev;
        hi = __uint_as_float(__float_as_uint(hi) & 0xFFFFC000u);  // keep 9 expl. mant bits
        sh_hi[tx]  = hi;
        sh_lo[tx]  = (float)(rev - (double)hi);
        sh_amp[tx] = (float)a;
    }
    __syncthreads();

    const int s = blockIdx.x * 256 + tx;      // sample index
    const float sp1 = (float)(s + 1);         // exact integer <= 2^14

    float acc0 = 0.f, acc1 = 0.f;
#pragma unroll 8
    for (int i = 0; i < OPC; i += 2) {
        float uh0 = sp1 * sh_hi[i + 0];                       // exact
        float uh1 = sp1 * sh_hi[i + 1];
        float t0  = __builtin_amdgcn_fractf(uh0);
        float t1  = __builtin_amdgcn_fractf(uh1);
        float r0  = __builtin_amdgcn_fractf(fmaf(sp1, sh_lo[i + 0], t0));
        float r1  = __builtin_amdgcn_fractf(fmaf(sp1, sh_lo[i + 1], t1));
        acc0 = fmaf(sh_amp[i + 0], __builtin_amdgcn_sinf(r0), acc0);
        acc1 = fmaf(sh_amp[i + 1], __builtin_amdgcn_sinf(r1), acc1);
    }
    partial[blockIdx.y * N_SAMP + s] = acc0 + acc1;
}

// ---------------------------------------------------------------------------
// Reduce the 16 chunk partials (values ~±60 each; f32 sum error negligible).
// ---------------------------------------------------------------------------
__global__ __launch_bounds__(256) void reduce_kernel(const float* __restrict__ partial,
                                                     float* __restrict__ out) {
    int s = blockIdx.x * 256 + threadIdx.x;
    float acc = 0.f;
#pragma unroll
    for (int c = 0; c < CHUNKS; ++c) acc += partial[c * N_SAMP + s];
    out[s] = acc;
}

// ---------------------------------------------------------------------------
// Fallback if d_ws is tiny: all-in-one, f64 per-term (slow but correct).
// ---------------------------------------------------------------------------
__global__ __launch_bounds__(256) void inline_kernel(const float* __restrict__ params,
                                                     float* __restrict__ out) {
    int s = blockIdx.x * 256 + threadIdx.x;
    if (s >= N_SAMP) return;
    const double sp1 = (double)(s + 1);
    double acc = 0.0;
    for (int o = 0; o < N_OSC; ++o) {
        double p0 = (double)params[2 * o + 0];
        double p1 = (double)params[2 * o + 1];
        double a  = sqrt(p0 * p0 + p1 * p1);
        double u  = sp1 * (atan2(p0, a) * 0.15915494309189535);
        float  r  = (float)(u - floor(u));
        acc += a * (double)__builtin_amdgcn_sinf(r);
    }
    out[s] = (float)acc;
}

extern "C" void kernel_launch(void* const* d_in, const int* in_sizes, int n_in,
                              void* d_out, int out_size, void* d_ws, size_t ws_size,
                              hipStream_t stream) {
    const float* params = (const float*)d_in[1];   // (2048, 2) f32
    float* out = (float*)d_out;

    const size_t part_bytes = (size_t)CHUNKS * N_SAMP * sizeof(float);  // 1 MB

    if (ws_size >= part_bytes) {
        float* partial = (float*)d_ws;
        synth_fused<<<dim3(N_SAMP / 256, CHUNKS), 256, 0, stream>>>(params, partial);
        reduce_kernel<<<N_SAMP / 256, 256, 0, stream>>>(partial, out);
    } else {
        inline_kernel<<<N_SAMP / 256, 256, 0, stream>>>(params, out);
    }
}

// Round 3
// 12.147 us; speedup vs baseline: 1.8902x; 1.1649x over previous
//
#include <hip/hip_runtime.h>
#include <math.h>

#define N_OSC 2048
#define N_SAMP 16384
#define NCHUNK 16                  // oscillator chunks (one wave-row each)
#define OPC (N_OSC / NCHUNK)       // 128 oscillators per chunk
#define SPB 64                     // samples per block (= wave width)
#define NTHREADS (NCHUNK * SPB)    // 1024 threads, 16 waves, 1 block/CU

// ---------------------------------------------------------------------------
// Single fused kernel.
//
// Math: ref output[s] = sum_o amp_o * sin((s+1) * atan2(p0, amp_o)),
//       amp_o = ||params[o]||.  With rev = atan2(p0, amp)/(2*pi) in (0,1/8],
//       the sin argument in REVOLUTIONS (v_sin_f32 domain) is
//       frac((s+1) * rev).  (s+1) <= 2^14 and rev <= 0.125, so the product
//       is <= 2048; frac() of the f32 product carries a quantization of at
//       most 2^-13 rev ~ 8e-4 rad -> output error ~0.05, threshold 25.6.
//
// Layout: wave = 64 consecutive samples x 1 oscillator chunk, so every LDS
// read in the main loop is wave-uniform (HW broadcast, conflict-free), and
// two oscillators' (rev, amp) pairs pack into one ds_read_b128.
// ---------------------------------------------------------------------------
__global__ __launch_bounds__(NTHREADS) void synth_one(const float* __restrict__ params,
                                                      float* __restrict__ out) {
    __shared__ alignas(16) float2 sh[N_OSC];     // (rev, amp)  16 KB
    __shared__ float red[NCHUNK][SPB];           // chunk partials  4 KB

    const int tid = threadIdx.x;

    // --- per-block oscillator prep (all f32, 2 oscillators per thread) ---
    {
        int o = tid;
        float p0 = params[2 * o], p1 = params[2 * o + 1];
        float a  = sqrtf(fmaf(p0, p0, p1 * p1));
        sh[o] = make_float2(atan2f(p0, a) * 0.15915494309189535f, a);
        o = tid + NTHREADS;
        p0 = params[2 * o]; p1 = params[2 * o + 1];
        a  = sqrtf(fmaf(p0, p0, p1 * p1));
        sh[o] = make_float2(atan2f(p0, a) * 0.15915494309189535f, a);
    }
    __syncthreads();

    // --- synthesis: this thread = sample s, oscillator chunk `chunk` ---
    const int chunk = tid >> 6;
    const int sl    = tid & 63;
    const int s     = blockIdx.x * SPB + sl;
    const float sp1 = (float)(s + 1);            // exact integer <= 2^14

    const float4* op4 = reinterpret_cast<const float4*>(&sh[chunk * OPC]);
    float acc0 = 0.f, acc1 = 0.f, acc2 = 0.f, acc3 = 0.f;
#pragma unroll 8
    for (int i = 0; i < OPC / 2; i += 2) {
        float4 a = op4[i];          // osc pair: (rev0, amp0, rev1, amp1)
        float4 b = op4[i + 1];      // osc pair: (rev2, amp2, rev3, amp3)
        acc0 = fmaf(a.y, __builtin_amdgcn_sinf(__builtin_amdgcn_fractf(sp1 * a.x)), acc0);
        acc1 = fmaf(a.w, __builtin_amdgcn_sinf(__builtin_amdgcn_fractf(sp1 * a.z)), acc1);
        acc2 = fmaf(b.y, __builtin_amdgcn_sinf(__builtin_amdgcn_fractf(sp1 * b.x)), acc2);
        acc3 = fmaf(b.w, __builtin_amdgcn_sinf(__builtin_amdgcn_fractf(sp1 * b.z)), acc3);
    }
    red[chunk][sl] = (acc0 + acc1) + (acc2 + acc3);
    __syncthreads();

    // --- in-LDS 16->1 chunk reduce; first wave writes 64 samples ---
    if (tid < SPB) {
        float a = 0.f;
#pragma unroll
        for (int c = 0; c < NCHUNK; ++c) a += red[c][tid];   // stride-1 lanes, conflict-free
        out[blockIdx.x * SPB + tid] = a;
    }
}

extern "C" void kernel_launch(void* const* d_in, const int* in_sizes, int n_in,
                              void* d_out, int out_size, void* d_ws, size_t ws_size,
                              hipStream_t stream) {
    const float* params = (const float*)d_in[1];   // (2048, 2) f32
    float* out = (float*)d_out;
    synth_one<<<N_SAMP / SPB, NTHREADS, 0, stream>>>(params, out);
}

// Round 4
// 12.091 us; speedup vs baseline: 1.8989x; 1.0046x over previous
//
#include <hip/hip_runtime.h>
#include <math.h>

#define N_OSC 2048
#define N_SAMP 16384
#define NCHUNK 16                  // oscillator chunks (one wave each)
#define OPC (N_OSC / NCHUNK)       // 128 oscillators per chunk
#define SPB 64                     // samples per block (= wave width)
#define NTHREADS (NCHUNK * SPB)    // 1024 threads, 16 waves, 1 block/CU

// ---------------------------------------------------------------------------
// Single fused kernel.
//
//   out[s] = sum_o amp_o * sin((s+1) * atan2(p0_o, amp_o)),  amp = ||params[o]||
//
// rev = atan2(p0, amp)/(2*pi) in (0, 1/8]; v_sin_f32 takes REVOLUTIONS, so
// the argument is frac((s+1)*rev) with (s+1) <= 2^14 (exact f32 integer).
// f32 quantization of the product (<= 2048) is 2^-13 rev ~ 8e-4 rad; the
// amp-weighted random sum over 2048 oscillators lands ~0.5 absmax vs the
// 25.6 threshold.
//
// Prep: branchless positive-args atan via one half-range reduction at
// tan(pi/8) + Cephes degree-9 odd polynomial (~2e-7 rad abs error ->
// ~0.1 extra output error). Avoids the ~100-instruction libm atan2f.
// ---------------------------------------------------------------------------

__device__ __forceinline__ float atan_pos(float x) {
    // x in (0, 1).  atan(x), error ~2-3 ulp (Cephes atanf coefficients).
    const float T = 0.41421356f;           // tan(pi/8)
    bool big = x > T;
    float z  = big ? (x - 1.0f) * __builtin_amdgcn_rcpf(x + 1.0f) : x;
    float z2 = z * z;
    float p  = fmaf(z2, 8.05374449538e-2f, -1.38776856032e-1f);
    p = fmaf(z2, p, 1.99777106478e-1f);
    p = fmaf(z2, p, -3.33329491539e-1f);
    float a = fmaf(z2 * z, p, z);
    return big ? a + 0.78539816339f : a;   // + pi/4 on the reduced branch
}

__global__ __launch_bounds__(NTHREADS) void synth_one(const float* __restrict__ params,
                                                      float* __restrict__ out) {
    __shared__ alignas(16) float2 sh[N_OSC];     // (rev, amp)  16 KB
    __shared__ float red[NCHUNK][SPB];           // chunk partials  4 KB

    const int tid = threadIdx.x;

    // --- per-block oscillator prep (2 oscillators per thread, all f32) ---
#pragma unroll
    for (int k = 0; k < 2; ++k) {
        int o = tid + k * NTHREADS;
        float p0 = params[2 * o], p1 = params[2 * o + 1];
        float a  = sqrtf(fmaf(p0, p0, p1 * p1));
        float x  = p0 * __builtin_amdgcn_rcpf(a);          // in (0,1)
        sh[o] = make_float2(atan_pos(x) * 0.15915494309189535f, a);
    }
    __syncthreads();

    // --- synthesis: thread = sample s x oscillator chunk ---
    const int chunk = tid >> 6;
    const int sl    = tid & 63;
    const int s     = blockIdx.x * SPB + sl;
    const float sp1 = (float)(s + 1);            // exact integer <= 2^14

    const float4* op4 = reinterpret_cast<const float4*>(&sh[chunk * OPC]);
    float acc0 = 0.f, acc1 = 0.f, acc2 = 0.f, acc3 = 0.f;
#pragma unroll 8
    for (int i = 0; i < OPC / 2; i += 2) {
        float4 a = op4[i];          // (rev0, amp0, rev1, amp1) — wave-uniform
        float4 b = op4[i + 1];      // (rev2, amp2, rev3, amp3)
        acc0 = fmaf(a.y, __builtin_amdgcn_sinf(__builtin_amdgcn_fractf(sp1 * a.x)), acc0);
        acc1 = fmaf(a.w, __builtin_amdgcn_sinf(__builtin_amdgcn_fractf(sp1 * a.z)), acc1);
        acc2 = fmaf(b.y, __builtin_amdgcn_sinf(__builtin_amdgcn_fractf(sp1 * b.x)), acc2);
        acc3 = fmaf(b.w, __builtin_amdgcn_sinf(__builtin_amdgcn_fractf(sp1 * b.z)), acc3);
    }
    red[chunk][sl] = (acc0 + acc1) + (acc2 + acc3);
    __syncthreads();

    // --- in-LDS 16->1 chunk reduce; first wave writes 64 samples ---
    if (tid < SPB) {
        float a = 0.f;
#pragma unroll
        for (int c = 0; c < NCHUNK; ++c) a += red[c][tid];   // stride-1, conflict-free
        out[blockIdx.x * SPB + tid] = a;
    }
}

extern "C" void kernel_launch(void* const* d_in, const int* in_sizes, int n_in,
                              void* d_out, int out_size, void* d_ws, size_t ws_size,
                              hipStream_t stream) {
    const float* params = (const float*)d_in[1];   // (2048, 2) f32
    float* out = (float*)d_out;
    synth_one<<<N_SAMP / SPB, NTHREADS, 0, stream>>>(params, out);
}